// Round 1
// baseline (213.789 us; speedup 1.0000x reference)
//
#include <hip/hip_runtime.h>

#define BB 32
#define NN 1024
#define EE 16384
#define DSS 8
#define HH 32

// prio[i*N+j] = max over all writes to (i,j) of (pass*E + e); -1 if untouched.
// pass 0 = (src,dst) assignment, pass 1 = (dst,src) assignment.
// max-priority == last sequential NumPy write -> deterministic last-write-wins.

__global__ void init_prio(int* __restrict__ prio) {
    int idx = blockIdx.x * blockDim.x + threadIdx.x;
    ((int4*)prio)[idx] = make_int4(-1, -1, -1, -1);
}

__global__ void build_prio(const int* __restrict__ edge_index, int* __restrict__ prio) {
    int t = blockIdx.x * blockDim.x + threadIdx.x;   // t in [0, 2E); t == pass*E + e
    int pass = t >= EE;
    int e = t - pass * EE;
    int src = edge_index[e];
    int dst = edge_index[EE + e];
    int i = pass ? dst : src;
    int j = pass ? src : dst;
    atomicMax(&prio[i * NN + j], t);
}

__global__ void score_kernel(const float* __restrict__ xyz,
                             const int* __restrict__ edge_index,
                             const int* __restrict__ edge_type,
                             const float* __restrict__ rest_len,
                             const float* __restrict__ type_emb,
                             const float* __restrict__ w1,
                             const float* __restrict__ b1,
                             const float* __restrict__ w2,
                             const float* __restrict__ b2,
                             float* __restrict__ score) {
    int idx = blockIdx.x * blockDim.x + threadIdx.x;  // b*E + e
    int e = idx & (EE - 1);
    int b = idx >> 14;                                 // E = 2^14
    int src = edge_index[e];
    int dst = edge_index[EE + e];
    const float* ps = xyz + ((size_t)b * NN + src) * 3;
    const float* pd = xyz + ((size_t)b * NN + dst) * 3;
    float dx = pd[0] - ps[0];
    float dy = pd[1] - ps[1];
    float dz = pd[2] - ps[2];
    float dist = sqrtf(dx * dx + dy * dy + dz * dz + 1e-12f);
    float rest = rest_len[e];
    int ty = edge_type[e];
    float f0 = dist, f1 = rest, f2 = dist - rest;

    float emb[DSS];
#pragma unroll
    for (int k = 0; k < DSS; ++k) emb[k] = type_emb[ty * DSS + k];

    float acc = b2[0];
#pragma unroll
    for (int j = 0; j < HH; ++j) {
        float h = b1[j];
        h = fmaf(f0, w1[0 * HH + j], h);
        h = fmaf(f1, w1[1 * HH + j], h);
        h = fmaf(f2, w1[2 * HH + j], h);
#pragma unroll
        for (int k = 0; k < DSS; ++k)
            h = fmaf(emb[k], w1[(3 + k) * HH + j], h);
        h = fmaxf(h, 0.0f);
        acc = fmaf(w2[j], h, acc);
    }
    score[idx] = acc;
}

// One block per output row i. prio row read once into registers; loop over b
// writing coalesced float4. Scattered locations look up score[b*E + e].
__global__ void fill_kernel(const int* __restrict__ prio,
                            const float* __restrict__ score,
                            const float* __restrict__ default_bias,
                            float* __restrict__ out) {
    int i = blockIdx.x;
    int j0 = threadIdx.x * 4;
    float defv = default_bias[0];
    int4 p = *(const int4*)(prio + (size_t)i * NN + j0);
    float* po = out + (size_t)i * NN + j0;

    if ((p.x & p.y & p.z & p.w) < 0) {        // all four == -1 (sign bits all set)
        float4 v = make_float4(defv, defv, defv, defv);
#pragma unroll 4
        for (int b = 0; b < BB; ++b)
            *(float4*)(po + (size_t)b * NN * NN) = v;
    } else {
        int ex = p.x & (EE - 1);
        int ey = p.y & (EE - 1);
        int ez = p.z & (EE - 1);
        int ew = p.w & (EE - 1);
        for (int b = 0; b < BB; ++b) {
            const float* sb = score + (size_t)b * EE;
            float4 v;
            v.x = (p.x >= 0) ? sb[ex] : defv;
            v.y = (p.y >= 0) ? sb[ey] : defv;
            v.z = (p.z >= 0) ? sb[ez] : defv;
            v.w = (p.w >= 0) ? sb[ew] : defv;
            *(float4*)(po + (size_t)b * NN * NN) = v;
        }
    }
}

extern "C" void kernel_launch(void* const* d_in, const int* in_sizes, int n_in,
                              void* d_out, int out_size, void* d_ws, size_t ws_size,
                              hipStream_t stream) {
    const float* xyz       = (const float*)d_in[0];
    const int*   edge_idx  = (const int*)  d_in[1];
    const int*   edge_type = (const int*)  d_in[2];
    const float* rest_len  = (const float*)d_in[3];
    const float* type_emb  = (const float*)d_in[4];
    const float* w1        = (const float*)d_in[5];
    const float* b1        = (const float*)d_in[6];
    const float* w2        = (const float*)d_in[7];
    const float* b2        = (const float*)d_in[8];
    const float* def_bias  = (const float*)d_in[9];
    float* out = (float*)d_out;

    int*   prio  = (int*)d_ws;                                   // N*N ints  = 4 MB
    float* score = (float*)((char*)d_ws + (size_t)NN * NN * 4);  // B*E floats = 2 MB

    init_prio <<<(NN * NN / 4) / 256, 256, 0, stream>>>(prio);
    build_prio<<<(2 * EE) / 256,      256, 0, stream>>>(edge_idx, prio);
    score_kernel<<<(BB * EE) / 256,   256, 0, stream>>>(xyz, edge_idx, edge_type, rest_len,
                                                        type_emb, w1, b1, w2, b2, score);
    fill_kernel<<<NN, 256, 0, stream>>>(prio, score, def_bias, out);
}

// Round 2
// 179.046 us; speedup vs baseline: 1.1940x; 1.1940x over previous
//
#include <hip/hip_runtime.h>

#define BB 32
#define NN 1024
#define EE 16384
#define DSS 8
#define HH 32

// prio[i*N+j] = max over all writes to (i,j) of (pass*E + e); -1 if untouched.
// pass 0 = (src,dst) assignment, pass 1 = (dst,src) assignment.
// max-priority == last sequential NumPy write -> deterministic last-write-wins.

// Fused: blocks [0,2048) compute per-(b,e) scores; blocks [2048,3072) init prio to -1.
__global__ void prep_kernel(const float* __restrict__ xyz,
                            const int* __restrict__ edge_index,
                            const int* __restrict__ edge_type,
                            const float* __restrict__ rest_len,
                            const float* __restrict__ type_emb,
                            const float* __restrict__ w1,
                            const float* __restrict__ b1,
                            const float* __restrict__ w2,
                            const float* __restrict__ b2,
                            float* __restrict__ score,
                            int* __restrict__ prio) {
    int blk = blockIdx.x;
    int tid = threadIdx.x;
    if (blk >= 2048) {                       // init role: 1024 blocks x 256 thr x int4 = N*N ints
        int idx = (blk - 2048) * 256 + tid;
        ((int4*)prio)[idx] = make_int4(-1, -1, -1, -1);
        return;
    }
    int idx = blk * 256 + tid;               // b*E + e
    int e = idx & (EE - 1);
    int b = idx >> 14;                       // E = 2^14
    int src = edge_index[e];
    int dst = edge_index[EE + e];
    const float* ps = xyz + ((size_t)b * NN + src) * 3;
    const float* pd = xyz + ((size_t)b * NN + dst) * 3;
    float dx = pd[0] - ps[0];
    float dy = pd[1] - ps[1];
    float dz = pd[2] - ps[2];
    float dist = sqrtf(dx * dx + dy * dy + dz * dz + 1e-12f);
    float rest = rest_len[e];
    int ty = edge_type[e];
    float f0 = dist, f1 = rest, f2 = dist - rest;

    float emb[DSS];
#pragma unroll
    for (int k = 0; k < DSS; ++k) emb[k] = type_emb[ty * DSS + k];

    float acc = b2[0];
#pragma unroll
    for (int j = 0; j < HH; ++j) {
        float h = b1[j];
        h = fmaf(f0, w1[0 * HH + j], h);
        h = fmaf(f1, w1[1 * HH + j], h);
        h = fmaf(f2, w1[2 * HH + j], h);
#pragma unroll
        for (int k = 0; k < DSS; ++k)
            h = fmaf(emb[k], w1[(3 + k) * HH + j], h);
        h = fmaxf(h, 0.0f);
        acc = fmaf(w2[j], h, acc);
    }
    score[idx] = acc;
}

__global__ void build_prio(const int* __restrict__ edge_index, int* __restrict__ prio) {
    int t = blockIdx.x * blockDim.x + threadIdx.x;   // t in [0, 2E); t == pass*E + e
    int pass = t >= EE;
    int e = t - pass * EE;
    int src = edge_index[e];
    int dst = edge_index[EE + e];
    int i = pass ? dst : src;
    int j = pass ? src : dst;
    atomicMax(&prio[i * NN + j], t);
}

// Block (i, bg): owns row i for batches [bg*16, bg*16+16).
// Phase 1: compact scattered columns of prio row into LDS.
// Phase 2: branch-free float4 default stream (memset-rate).
// Phase 3: scalar fixups -- lines are dirty in L2 from phase 2, no extra HBM traffic.
__global__ void fill_kernel(const int* __restrict__ prio,
                            const float* __restrict__ score,
                            const float* __restrict__ default_bias,
                            float* __restrict__ out) {
    __shared__ int s_col[1024];   // worst case: every column scattered
    __shared__ int s_e[1024];
    __shared__ int s_cnt;
    int i = blockIdx.x;
    int bg = blockIdx.y;          // batch group: 16 batches each
    int tid = threadIdx.x;

    if (tid == 0) s_cnt = 0;
    __syncthreads();

    int4 p = *(const int4*)(prio + (size_t)i * NN + tid * 4);
    if (p.x >= 0) { int s = atomicAdd(&s_cnt, 1); s_col[s] = tid * 4 + 0; s_e[s] = p.x & (EE - 1); }
    if (p.y >= 0) { int s = atomicAdd(&s_cnt, 1); s_col[s] = tid * 4 + 1; s_e[s] = p.y & (EE - 1); }
    if (p.z >= 0) { int s = atomicAdd(&s_cnt, 1); s_col[s] = tid * 4 + 2; s_e[s] = p.z & (EE - 1); }
    if (p.w >= 0) { int s = atomicAdd(&s_cnt, 1); s_col[s] = tid * 4 + 3; s_e[s] = p.w & (EE - 1); }

    float defv = default_bias[0];
    float4 dv = make_float4(defv, defv, defv, defv);
    float* base = out + (size_t)(bg * 16) * NN * NN + (size_t)i * NN + tid * 4;
#pragma unroll
    for (int bb = 0; bb < 16; ++bb)
        *(float4*)(base + (size_t)bb * NN * NN) = dv;

    __syncthreads();              // orders phase-2 stores before phase-3 overwrites (block-local)

    int total = s_cnt << 4;       // cnt * 16 batches
    for (int w = tid; w < total; w += 256) {
        int c = w >> 4;
        int b = (bg << 4) + (w & 15);
        out[(size_t)b * NN * NN + (size_t)i * NN + s_col[c]] = score[(size_t)b * EE + s_e[c]];
    }
}

extern "C" void kernel_launch(void* const* d_in, const int* in_sizes, int n_in,
                              void* d_out, int out_size, void* d_ws, size_t ws_size,
                              hipStream_t stream) {
    const float* xyz       = (const float*)d_in[0];
    const int*   edge_idx  = (const int*)  d_in[1];
    const int*   edge_type = (const int*)  d_in[2];
    const float* rest_len  = (const float*)d_in[3];
    const float* type_emb  = (const float*)d_in[4];
    const float* w1        = (const float*)d_in[5];
    const float* b1        = (const float*)d_in[6];
    const float* w2        = (const float*)d_in[7];
    const float* b2        = (const float*)d_in[8];
    const float* def_bias  = (const float*)d_in[9];
    float* out = (float*)d_out;

    int*   prio  = (int*)d_ws;                                   // N*N ints  = 4 MB
    float* score = (float*)((char*)d_ws + (size_t)NN * NN * 4);  // B*E floats = 2 MB

    prep_kernel<<<3072, 256, 0, stream>>>(xyz, edge_idx, edge_type, rest_len,
                                          type_emb, w1, b1, w2, b2, score, prio);
    build_prio<<<(2 * EE) / 256, 256, 0, stream>>>(edge_idx, prio);
    fill_kernel<<<dim3(NN, 2), 256, 0, stream>>>(prio, score, def_bias, out);
}